// Round 1
// baseline (2101.748 us; speedup 1.0000x reference)
//
#include <hip/hip_runtime.h>

// Problem constants
#define CH   256
#define HW   64
#define HP   66          // padded 66x66
#define LSTRIDE 68       // LDS row stride (floats), 16B-aligned rows
#define NB   4           // batch

typedef __attribute__((address_space(1))) const void* gptr_t;
typedef __attribute__((address_space(3))) void* lptr_t;

__device__ __forceinline__ void gll_b32(const float* g, float* l) {
  __builtin_amdgcn_global_load_lds((gptr_t)g, (lptr_t)l, 4, 0, 0);
}
__device__ __forceinline__ void gll_b128(const float* g, float* l) {
  __builtin_amdgcn_global_load_lds((gptr_t)g, (lptr_t)l, 16, 0, 0);
}

// ---------------------------------------------------------------------------
// Direct 3x3 conv. Block = (b, o). 256 threads, each computes a 4x4 pixel tile.
// Input channel staged into padded 66x(68) LDS tile each c-iteration.
// INPAD:  input already stored padded (66x66 per channel) -> stage directly.
// OUTPAD: output written in padded 66x66 layout (borders zeroed).
// RELU:   out = relu(conv+bias) + resid   (conv1)
// ---------------------------------------------------------------------------
template<bool RELU, bool INPAD, bool OUTPAD>
__global__ __launch_bounds__(256) void conv3x3_k(
    const float* __restrict__ in, const float* __restrict__ w,
    const float* __restrict__ bias, const float* __restrict__ resid,
    float* __restrict__ out, int O)
{
  __shared__ float chan[HP * LSTRIDE];
  const int t = threadIdx.x;
  const int b = blockIdx.x / O;
  const int o = blockIdx.x % O;
  const int lane = t & 63, wave = t >> 6;
  const int x0 = (t & 15) * 4, y0 = (t >> 4) * 4;

  if (!INPAD) {
    for (int i = t; i < HP * LSTRIDE; i += 256) chan[i] = 0.f;
  }
  if (OUTPAD) {
    // zero the 260 border elements of this output channel every launch
    float* oc = out + (size_t)(b * O + o) * (HP * HP);
    for (int e = t; e < 260; e += 256) {
      int r, cc;
      if (e < 66)       { r = 0;       cc = e; }
      else if (e < 132) { r = 65;      cc = e - 66; }
      else if (e < 196) { r = e - 131; cc = 0; }
      else              { r = e - 195; cc = 65; }
      oc[r * 66 + cc] = 0.f;
    }
  }
  __syncthreads();

  const float* in_b = in + (size_t)b * CH * (INPAD ? HP * HP : HW * HW);

  float acc[4][4];
  #pragma unroll
  for (int a = 0; a < 4; ++a)
    #pragma unroll
    for (int d = 0; d < 4; ++d) acc[a][d] = 0.f;

  for (int c = 0; c < CH; ++c) {
    if (!INPAD) {
      const float* src = in_b + (size_t)c * (HW * HW) + lane;
      #pragma unroll
      for (int rr = 0; rr < 16; ++rr) {
        const int r = wave + rr * 4;                   // rows 0..63
        gll_b32(src + r * HW, &chan[(r + 1) * LSTRIDE + 1]);
      }
    } else {
      const float* src = in_b + (size_t)c * (HP * HP);
      for (int i = t; i < HP * HP; i += 256)
        chan[(i / 66) * LSTRIDE + (i % 66)] = src[i];
    }
    __syncthreads();

    const float* wp = w + ((size_t)o * CH + c) * 9;    // (o,c) uniform -> s_load
    float wk[9];
    #pragma unroll
    for (int k = 0; k < 9; ++k) wk[k] = wp[k];

    float win[6][6];
    #pragma unroll
    for (int r = 0; r < 6; ++r) {
      const float4 v = *(const float4*)&chan[(y0 + r) * LSTRIDE + x0];
      const float2 u = *(const float2*)&chan[(y0 + r) * LSTRIDE + x0 + 4];
      win[r][0] = v.x; win[r][1] = v.y; win[r][2] = v.z; win[r][3] = v.w;
      win[r][4] = u.x; win[r][5] = u.y;
    }
    #pragma unroll
    for (int ky = 0; ky < 3; ++ky)
      #pragma unroll
      for (int kx = 0; kx < 3; ++kx) {
        const float wkk = wk[ky * 3 + kx];
        #pragma unroll
        for (int dy = 0; dy < 4; ++dy)
          #pragma unroll
          for (int dx = 0; dx < 4; ++dx)
            acc[dy][dx] = fmaf(wkk, win[dy + ky][dx + kx], acc[dy][dx]);
      }
    __syncthreads();
  }

  const float bv = bias[o];
  if (!OUTPAD) {
    #pragma unroll
    for (int dy = 0; dy < 4; ++dy) {
      const int y = y0 + dy;
      const size_t base = (((size_t)(b * O + o)) * HW + y) * HW + x0;
      float v0 = acc[dy][0] + bv, v1 = acc[dy][1] + bv,
            v2 = acc[dy][2] + bv, v3 = acc[dy][3] + bv;
      if (RELU) {
        v0 = fmaxf(v0, 0.f); v1 = fmaxf(v1, 0.f);
        v2 = fmaxf(v2, 0.f); v3 = fmaxf(v3, 0.f);
        const float4 xr = *(const float4*)(resid + base);
        v0 += xr.x; v1 += xr.y; v2 += xr.z; v3 += xr.w;
      }
      float4 r; r.x = v0; r.y = v1; r.z = v2; r.w = v3;
      *(float4*)(out + base) = r;
    }
  } else {
    float* oc = out + (size_t)(b * O + o) * (HP * HP);
    #pragma unroll
    for (int dy = 0; dy < 4; ++dy) {
      const int y = y0 + dy;
      #pragma unroll
      for (int dx = 0; dx < 4; ++dx)
        oc[(y + 1) * 66 + (x0 + 1) + dx] = acc[dy][dx] + bv;
    }
  }
}

// ---------------------------------------------------------------------------
// dw (O,C,3,3) -> dwT[(c*9+n)*256 + o]  (GEMM-friendly layout)
// ---------------------------------------------------------------------------
__global__ __launch_bounds__(256) void transpose_dw_k(
    const float* __restrict__ dw, float* __restrict__ dwT)
{
  const int idx = blockIdx.x * 256 + threadIdx.x;   // (c*9+n)*256 + o, exact grid
  const int o = idx & 255;
  const int n = (idx >> 8) % 9;
  const int c = idx / (9 * 256);
  dwT[idx] = dw[((size_t)o * CH + c) * 9 + n];
}

// ---------------------------------------------------------------------------
// Bilinear table: per (b,i,n,j): 4 gather indices into 66x66 + 4 weights.
// Replicates reference: fx=floor(raw p); q* = clip; p clipped after.
// ---------------------------------------------------------------------------
__global__ __launch_bounds__(256) void build_table_k(
    const float* __restrict__ offs, float* __restrict__ table)
{
  const int e = blockIdx.x * 256 + threadIdx.x;     // ((b*64+i)*9+n)*64+j
  const int j = e & 63;
  const int n = (e >> 6) % 9;
  const int i = (e / 576) % 64;
  const int b = e / 36864;
  const int ki = n / 3, kj = n % 3;

  const float offr = offs[(((size_t)b * 18 + n) * HW + i) * HW + j];
  const float offc = offs[(((size_t)b * 18 + 9 + n) * HW + i) * HW + j];

  const float prow = offr + (float)(ki - 1) + (float)(i + 1);
  const float pcol = offc + (float)(kj - 1) + (float)(j + 1);
  const float fx = floorf(prow), fy = floorf(pcol);
  const float qlx = fminf(fmaxf(fx, 0.f), 65.f);
  const float qly = fminf(fmaxf(fy, 0.f), 65.f);
  const float qrx = fminf(fmaxf(fx + 1.f, 0.f), 65.f);
  const float qry = fminf(fmaxf(fy + 1.f, 0.f), 65.f);
  const float pr  = fminf(fmaxf(prow, 0.f), 65.f);
  const float pc  = fminf(fmaxf(pcol, 0.f), 65.f);

  const float glt = (1.f + qlx - pr) * (1.f + qly - pc);
  const float grb = (1.f - qrx + pr) * (1.f - qry + pc);
  const float glb = (1.f + qlx - pr) * (1.f - qry + pc);
  const float grt = (1.f - qrx + pr) * (1.f + qly - pc);

  float* tp = table + (size_t)e * 8;
  int* ip = (int*)tp;
  ip[0] = (int)qlx * 66 + (int)qly;
  ip[1] = (int)qrx * 66 + (int)qry;
  ip[2] = (int)qlx * 66 + (int)qry;
  ip[3] = (int)qrx * 66 + (int)qly;
  tp[4] = glt; tp[5] = grb; tp[6] = glb; tp[7] = grt;
}

// ---------------------------------------------------------------------------
// Final deform conv + residual. Block = (b, output row i). 256 threads.
// Per c: stage padded channel (4356 f) to LDS, compute samp[9][64],
// then GEMM: each thread owns 2 output channels x 32 pixels.
// ---------------------------------------------------------------------------
__global__ __launch_bounds__(256) void deform_final_k(
    const float* __restrict__ res2p, const float* __restrict__ table,
    const float* __restrict__ dwT, const float* __restrict__ x,
    float* __restrict__ out)
{
  __shared__ float chan[4416];       // 66*66 = 4356 used
  __shared__ float samp[9][64];
  __shared__ float dws[9][256];

  const int t = threadIdx.x;
  const int b = blockIdx.x >> 6;
  const int i = blockIdx.x & 63;
  const int lane = t & 63, wave = t >> 6;
  const int j = lane;
  const int nsamp = (wave == 0) ? 3 : 2;   // wave w handles n = w, w+4, (w+8)

  int   gi[3][4];
  float gw[3][4];
  #pragma unroll
  for (int s = 0; s < 3; ++s) {
    if (s < nsamp) {
      const int n = wave + 4 * s;
      const float* tp = table + ((((size_t)b * 64 + i) * 9 + n) * 64 + j) * 8;
      const int4   iv = *(const int4*)tp;
      const float4 wv = *(const float4*)(tp + 4);
      gi[s][0] = iv.x; gi[s][1] = iv.y; gi[s][2] = iv.z; gi[s][3] = iv.w;
      gw[s][0] = wv.x; gw[s][1] = wv.y; gw[s][2] = wv.z; gw[s][3] = wv.w;
    }
  }

  const int o0  = (t & 127) * 2;
  const int pxb = (t >> 7) * 32;
  float acc0[32], acc1[32];
  #pragma unroll
  for (int q = 0; q < 32; ++q) { acc0[q] = 0.f; acc1[q] = 0.f; }

  const float* chb = res2p + (size_t)b * CH * (HP * HP);

  for (int c = 0; c < CH; ++c) {
    const float* src = chb + (size_t)c * (HP * HP);
    #pragma unroll
    for (int ch2 = 0; ch2 < 5; ++ch2) {
      const int chunk = wave + ch2 * 4;
      if (chunk < 17)
        gll_b128(src + chunk * 256 + lane * 4, &chan[chunk * 256]);
    }
    if (t < 4) chan[4352 + t] = src[4352 + t];

    const float4* dsrc = (const float4*)(dwT + (size_t)c * 2304);
    float4* ddst = (float4*)&dws[0][0];
    #pragma unroll
    for (int k2 = 0; k2 < 3; ++k2) {
      const int k = t + k2 * 256;
      if (k < 576) ddst[k] = dsrc[k];
    }
    __syncthreads();

    #pragma unroll
    for (int s = 0; s < 3; ++s) {
      if (s < nsamp) {
        const int n = wave + 4 * s;
        samp[n][j] = gw[s][0] * chan[gi[s][0]] + gw[s][1] * chan[gi[s][1]]
                   + gw[s][2] * chan[gi[s][2]] + gw[s][3] * chan[gi[s][3]];
      }
    }
    __syncthreads();

    #pragma unroll
    for (int n = 0; n < 9; ++n) {
      const float2 wv = *(const float2*)&dws[n][o0];
      #pragma unroll
      for (int q = 0; q < 8; ++q) {
        const float4 sv = *(const float4*)&samp[n][pxb + 4 * q];
        acc0[4*q+0] = fmaf(wv.x, sv.x, acc0[4*q+0]);
        acc0[4*q+1] = fmaf(wv.x, sv.y, acc0[4*q+1]);
        acc0[4*q+2] = fmaf(wv.x, sv.z, acc0[4*q+2]);
        acc0[4*q+3] = fmaf(wv.x, sv.w, acc0[4*q+3]);
        acc1[4*q+0] = fmaf(wv.y, sv.x, acc1[4*q+0]);
        acc1[4*q+1] = fmaf(wv.y, sv.y, acc1[4*q+1]);
        acc1[4*q+2] = fmaf(wv.y, sv.z, acc1[4*q+2]);
        acc1[4*q+3] = fmaf(wv.y, sv.w, acc1[4*q+3]);
      }
    }
    __syncthreads();
  }

  #pragma unroll
  for (int oo = 0; oo < 2; ++oo) {
    const int o = o0 + oo;
    const float* accp = oo ? acc1 : acc0;
    const size_t base = (((size_t)b * CH + o) * HW + i) * HW + pxb;
    #pragma unroll
    for (int q = 0; q < 8; ++q) {
      const float4 xv = *(const float4*)(x + base + 4 * q);
      float4 r;
      r.x = accp[4*q+0] + xv.x;
      r.y = accp[4*q+1] + xv.y;
      r.z = accp[4*q+2] + xv.z;
      r.w = accp[4*q+3] + xv.w;
      *(float4*)(out + base + 4 * q) = r;
    }
  }
}

// ---------------------------------------------------------------------------
// Workspace layout (floats):
//   [0        .. 4,194,304)  res1   (reused after conv2: table @0, dwT @1,179,648)
//   [4,194,304 .. 8,654,848) res2p  (4 x 256 x 66 x 66)
//   [8,654,848 .. 8,949,760) offset (4 x 18 x 64 x 64)
// Total 35.8 MB.
// ---------------------------------------------------------------------------
extern "C" void kernel_launch(void* const* d_in, const int* in_sizes, int n_in,
                              void* d_out, int out_size, void* d_ws, size_t ws_size,
                              hipStream_t stream) {
  (void)in_sizes; (void)n_in; (void)out_size; (void)ws_size;
  const float* x  = (const float*)d_in[0];
  const float* w1 = (const float*)d_in[1];
  const float* b1 = (const float*)d_in[2];
  const float* w2 = (const float*)d_in[3];
  const float* b2 = (const float*)d_in[4];
  const float* pw = (const float*)d_in[5];
  const float* pb = (const float*)d_in[6];
  const float* dw = (const float*)d_in[7];
  float* out = (float*)d_out;
  float* ws  = (float*)d_ws;

  float* res1  = ws;
  float* res2p = ws + 4194304;
  float* offs  = ws + 8654848;
  float* table = ws;             // reuse res1 region after conv2
  float* dwT   = ws + 1179648;   // also inside res1 region

  // 1. res1 = relu(conv(x,w1)+b1) + x
  conv3x3_k<true, false, false><<<NB * CH, 256, 0, stream>>>(x, w1, b1, x, res1, CH);
  // 2. res2p = conv(res1,w2)+b2, stored padded 66x66
  conv3x3_k<false, false, true><<<NB * CH, 256, 0, stream>>>(res1, w2, b2, nullptr, res2p, CH);
  // 3. offset = conv(res2, p_w)+p_b  (reads padded input directly)
  conv3x3_k<false, true, false><<<NB * 18, 256, 0, stream>>>(res2p, pw, pb, nullptr, offs, 18);
  // 4. dw transpose (res1 region now dead)
  transpose_dw_k<<<2304, 256, 0, stream>>>(dw, dwT);
  // 5. bilinear table
  build_table_k<<<576, 256, 0, stream>>>(offs, table);
  // 6. deform GEMM + residual
  deform_final_k<<<NB * HW, 256, 0, stream>>>(res2p, table, dwT, x, out);
}

// Round 2
// 182.747 us; speedup vs baseline: 11.5008x; 11.5008x over previous
//
#include <hip/hip_runtime.h>

#define HW 64
#define HP 66
#define NB 4
#define CH 256

typedef __attribute__((address_space(1))) const void* gptr_t;
typedef __attribute__((address_space(3))) void* lptr_t;
typedef __attribute__((ext_vector_type(8))) short bf8v;   // 8 bf16 bit-patterns
typedef __attribute__((ext_vector_type(4))) float f32x4;

__device__ __forceinline__ void gll16(const void* g, void* l) {
  __builtin_amdgcn_global_load_lds((gptr_t)g, (lptr_t)l, 16, 0, 0);
}
__device__ __forceinline__ ushort f2b(float f) {
  union { float f; uint u; } v; v.f = f;
  uint r = v.u + 0x7FFF + ((v.u >> 16) & 1);
  return (ushort)(r >> 16);
}
__device__ __forceinline__ float b2f(ushort b) {
  union { uint u; float f; } v; v.u = ((uint)b) << 16;
  return v.f;
}

// ---------------------------------------------------------------------------
// pack_x: x NCHW f32 -> xpad [4][66][66][256] bf16 (interior) + xt NHWC f32
// block = (b, row i), 256 threads
// ---------------------------------------------------------------------------
__global__ __launch_bounds__(256) void pack_x_k(
    const float* __restrict__ x, ushort* __restrict__ xpad, float* __restrict__ xt)
{
  __shared__ float tile[64][260];
  const int t = threadIdx.x, b = blockIdx.x >> 6, i = blockIdx.x & 63;
  const int wave = t >> 6, l = t & 63;
  const float* src = x + (size_t)b * CH * 4096 + (size_t)i * 64;
  for (int cc = 0; cc < 64; ++cc) {
    const int c = cc * 4 + wave;
    tile[l][c] = src[(size_t)c * 4096 + l];
  }
  __syncthreads();
  const int j = t >> 2, cq = t & 3;
  float* xto = xt + ((size_t)b * 4096 + i * 64 + j) * 256;
  ushort* xpo = xpad + ((size_t)b * 4356 + (i + 1) * 66 + (j + 1)) * 256;
  #pragma unroll
  for (int q = 0; q < 16; ++q) {
    const int c = cq * 64 + q * 4;
    const float4 v = *(const float4*)&tile[j][c];
    *(float4*)&xto[c] = v;
    ushort4 s; s.x = f2b(v.x); s.y = f2b(v.y); s.z = f2b(v.z); s.w = f2b(v.w);
    *(ushort4*)&xpo[c] = s;
  }
}

// ---------------------------------------------------------------------------
// pack_w: w1/w2/dw -> [cb8][tap9][o256][kc4][8] bf16 ; pw -> [cb][tap][32][kc][8]
// ---------------------------------------------------------------------------
__global__ __launch_bounds__(256) void pack_w_k(
    const float* __restrict__ w1, const float* __restrict__ w2,
    const float* __restrict__ dw, const float* __restrict__ pw,
    const float* __restrict__ pb,
    ushort* __restrict__ wpk1, ushort* __restrict__ wpk2,
    ushort* __restrict__ dwpk, ushort* __restrict__ wpkO, float* __restrict__ pbias)
{
  const int id = blockIdx.x * 256 + threadIdx.x;
  if (id < 3 * 73728) {
    const int tsel = id / 73728, r = id % 73728;
    const int kc = r & 3, o = (r >> 2) & 255, ct = r >> 10;
    const int cb = ct / 9, tap = ct % 9;
    const float* w = (tsel == 0) ? w1 : (tsel == 1) ? w2 : dw;
    const float* s = w + ((size_t)o * CH + cb * 32 + kc * 8) * 9 + tap;
    ushort* d = ((tsel == 0) ? wpk1 : (tsel == 1) ? wpk2 : dwpk) + (size_t)r * 8;
    #pragma unroll
    for (int j = 0; j < 8; ++j) d[j] = f2b(s[j * 9]);
  } else if (id < 3 * 73728 + 9216) {
    const int r = id - 3 * 73728;
    const int kc = r & 3, o = (r >> 2) & 31, ct = r >> 7;
    const int cb = ct / 9, tap = ct % 9;
    ushort* d = wpkO + (size_t)r * 8;
    if (o < 18) {
      const float* s = pw + ((size_t)o * CH + cb * 32 + kc * 8) * 9 + tap;
      #pragma unroll
      for (int j = 0; j < 8; ++j) d[j] = f2b(s[j * 9]);
    } else {
      #pragma unroll
      for (int j = 0; j < 8; ++j) d[j] = 0;
    }
  }
  if (id < 32) pbias[id] = (id < 18) ? pb[id] : 0.f;
}

// ---------------------------------------------------------------------------
// Implicit-GEMM 3x3 conv via MFMA. BM=128 px (2 rows), BN o-channels.
// Swapped operands: D[o][px].  OUTMODE 0: bias+relu+resid -> bf16 pad out
//                              OUTMODE 1: bias -> bf16 pad out
//                              OUTMODE 2: bias -> f32 [b][px][32] out
// ---------------------------------------------------------------------------
template<int BN, int OUTMODE>
__global__ __launch_bounds__(256, 1) void conv_mfma(
    const ushort* __restrict__ apad, const ushort* __restrict__ wpk,
    const float* __restrict__ bias, const float* __restrict__ xt,
    void* __restrict__ outp)
{
  constexpr int OTOT = (BN == 128) ? 256 : 32;
  constexpr int FO = (BN == 128) ? 4 : 2;
  constexpr int FP = (BN == 128) ? 4 : 2;
  constexpr int EPT = BN / 16;            // gll w16 instrs per tap for B
  __shared__ __align__(16) ushort patch[17 * 512];      // 17408 B
  __shared__ __align__(16) ushort b9[9 * BN * 32];

  const int t = threadIdx.x, wave = t >> 6, l = t & 63;
  const int mt = (BN == 128) ? (blockIdx.x & 127) : blockIdx.x;
  const int ot = (BN == 128) ? (blockIdx.x >> 7) : 0;
  const int b = mt >> 5, i0 = (mt & 31) * 2;
  const int oB = (BN == 128) ? ((wave >> 1) * 64) : 0;
  const int pB = (BN == 128) ? ((wave & 1) * 64) : (wave * 32);
  const int ln = l & 15, kc8 = (l >> 4) * 8;

  f32x4 acc[FO][FP];
  #pragma unroll
  for (int a = 0; a < FO; ++a)
    #pragma unroll
    for (int d = 0; d < FP; ++d) acc[a][d] = (f32x4){0.f, 0.f, 0.f, 0.f};

  const ushort* xrow = apad + ((size_t)b * 4356 + i0 * 66) * 256;

  for (int cb = 0; cb < 8; ++cb) {
    __syncthreads();
    // stage A-patch: 264 pixel-chunks of 64B (+ tail overrun into slack)
    for (int e = wave; e < 17; e += 4) {
      const ushort* s = xrow + (size_t)(e * 16 + (l >> 2)) * 256 + cb * 32 + (l & 3) * 8;
      gll16(s, (ushort*)patch + e * 512);
    }
    // stage B: 9 taps x BN x 32
    for (int q = wave; q < 9 * EPT; q += 4) {
      const int tap = q / EPT, e = q % EPT;
      const ushort* s = wpk + ((size_t)(cb * 9 + tap) * OTOT + ot * BN) * 32 + e * 512 + l * 8;
      gll16(s, (ushort*)b9 + tap * BN * 32 + e * 512);
    }
    __syncthreads();

    #pragma unroll
    for (int tap = 0; tap < 9; ++tap) {
      const int ky = tap / 3, kx = tap % 3;
      bf8v wf[FO], pf[FP];
      #pragma unroll
      for (int fo = 0; fo < FO; ++fo)
        wf[fo] = *(const bf8v*)&b9[(tap * BN + oB + fo * 16 + ln) * 32 + kc8];
      #pragma unroll
      for (int fp = 0; fp < FP; ++fp) {
        const int pxl = pB + fp * 16 + ln;
        const int p = ((pxl >> 6) + ky) * 66 + (pxl & 63) + kx;
        pf[fp] = *(const bf8v*)&patch[p * 32 + kc8];
      }
      #pragma unroll
      for (int fo = 0; fo < FO; ++fo)
        #pragma unroll
        for (int fp = 0; fp < FP; ++fp)
          acc[fo][fp] = __builtin_amdgcn_mfma_f32_16x16x32_bf16(wf[fo], pf[fp], acc[fo][fp], 0, 0, 0);
    }
  }

  // epilogue: D row = o = (l>>4)*4+r, col = px = l&15
  #pragma unroll
  for (int fo = 0; fo < FO; ++fo) {
    #pragma unroll
    for (int fp = 0; fp < FP; ++fp) {
      const f32x4 a = acc[fo][fp];
      const int o = ot * 128 + oB + fo * 16 + (l >> 4) * 4;
      const int pxl = pB + fp * 16 + ln;
      const int i = i0 + (pxl >> 6), j = pxl & 63;
      const float4 bv = *(const float4*)&bias[o];
      float v0 = a[0] + bv.x, v1 = a[1] + bv.y, v2 = a[2] + bv.z, v3 = a[3] + bv.w;
      if (OUTMODE == 0) {
        const float4 xr = *(const float4*)&xt[((size_t)b * 4096 + i * 64 + j) * 256 + o];
        v0 = fmaxf(v0, 0.f) + xr.x; v1 = fmaxf(v1, 0.f) + xr.y;
        v2 = fmaxf(v2, 0.f) + xr.z; v3 = fmaxf(v3, 0.f) + xr.w;
      }
      if (OUTMODE == 2) {
        float* op = (float*)outp + ((size_t)b * 4096 + i * 64 + j) * 32 + o;
        float4 r; r.x = v0; r.y = v1; r.z = v2; r.w = v3;
        *(float4*)op = r;
      } else {
        ushort* op = (ushort*)outp + ((size_t)b * 4356 + (i + 1) * 66 + (j + 1)) * 256 + o;
        ushort4 s; s.x = f2b(v0); s.y = f2b(v1); s.z = f2b(v2); s.w = f2b(v3);
        *(ushort4*)op = s;
      }
    }
  }
}

// ---------------------------------------------------------------------------
// Bilinear table (same math as passing round-0 version; offs layout [b][px][32])
// ---------------------------------------------------------------------------
__global__ __launch_bounds__(256) void build_table_k(
    const float* __restrict__ offs, float* __restrict__ table)
{
  const int e = blockIdx.x * 256 + threadIdx.x;     // ((b*64+i)*9+n)*64+j
  const int j = e & 63;
  const int n = (e >> 6) % 9;
  const int i = (e / 576) % 64;
  const int b = e / 36864;
  const int ki = n / 3, kj = n % 3;

  const float offr = offs[((size_t)b * 4096 + i * 64 + j) * 32 + n];
  const float offc = offs[((size_t)b * 4096 + i * 64 + j) * 32 + 9 + n];

  const float prow = offr + (float)(ki - 1) + (float)(i + 1);
  const float pcol = offc + (float)(kj - 1) + (float)(j + 1);
  const float fx = floorf(prow), fy = floorf(pcol);
  const float qlx = fminf(fmaxf(fx, 0.f), 65.f);
  const float qly = fminf(fmaxf(fy, 0.f), 65.f);
  const float qrx = fminf(fmaxf(fx + 1.f, 0.f), 65.f);
  const float qry = fminf(fmaxf(fy + 1.f, 0.f), 65.f);
  const float pr  = fminf(fmaxf(prow, 0.f), 65.f);
  const float pc  = fminf(fmaxf(pcol, 0.f), 65.f);

  const float glt = (1.f + qlx - pr) * (1.f + qly - pc);
  const float grb = (1.f - qrx + pr) * (1.f - qry + pc);
  const float glb = (1.f + qlx - pr) * (1.f - qry + pc);
  const float grt = (1.f - qrx + pr) * (1.f + qly - pc);

  float* tp = table + (size_t)e * 8;
  int* ip = (int*)tp;
  ip[0] = (int)qlx * 66 + (int)qly;
  ip[1] = (int)qrx * 66 + (int)qry;
  ip[2] = (int)qlx * 66 + (int)qry;
  ip[3] = (int)qrx * 66 + (int)qly;
  tp[4] = glt; tp[5] = grb; tp[6] = glb; tp[7] = grt;
}

// ---------------------------------------------------------------------------
// Deform GEMM + residual. block = (b, row i). 512 threads = 8 waves.
// Per 32-ch block: sample A[9][64px][32c] bf16 from res2pad (L2 gathers),
// then 9 MFMA K-steps vs double-buffered dw tiles. D[px][o] -> NCHW + x.
// ---------------------------------------------------------------------------
__global__ __launch_bounds__(512, 1) void deform_mfma(
    const ushort* __restrict__ res2pad, const float* __restrict__ table,
    const ushort* __restrict__ dwpk, const float* __restrict__ x,
    float* __restrict__ out)
{
  __shared__ __align__(16) ushort samp[9 * 64 * 32];   // 36864 B
  __shared__ __align__(16) ushort bw[2][256 * 32];     // 2 x 16384 B
  __shared__ __align__(16) int   tbl_i[576 * 4];
  __shared__ __align__(16) float tbl_w[576 * 4];

  const int t = threadIdx.x, wave = t >> 6, l = t & 63;
  const int b = blockIdx.x >> 6, i = blockIdx.x & 63;
  const int ln = l & 15, kc8 = (l >> 4) * 8;

  // stage bilinear table for this (b,i): 576 entries
  for (int u = t; u < 576; u += 512) {
    const float* tp = table + ((size_t)(b * 64 + i) * 9 * 64 + u) * 8;
    *(int4*)&tbl_i[u * 4] = *(const int4*)tp;
    *(float4*)&tbl_w[u * 4] = *(const float4*)(tp + 4);
  }
  __syncthreads();

  f32x4 acc[4][2];
  #pragma unroll
  for (int a = 0; a < 4; ++a) { acc[a][0] = (f32x4){0,0,0,0}; acc[a][1] = (f32x4){0,0,0,0}; }

  const ushort* res2b = res2pad + (size_t)b * 4356 * 256;

  for (int cb = 0; cb < 8; ++cb) {
    // ---- sample phase: 2304 units = (tap, px, i16) ----
    #pragma unroll
    for (int k = 0; k < 5; ++k) {
      const int u = t + k * 512;
      if (u < 2304) {
        const int tap = u >> 8, px = (u >> 2) & 63, i16 = u & 3;
        const int e = tap * 64 + px;
        const int4 iv = *(const int4*)&tbl_i[e * 4];
        const float4 gv = *(const float4*)&tbl_w[e * 4];
        const ushort* base = res2b + cb * 32 + i16 * 8;
        const bf8v c0 = *(const bf8v*)(base + (size_t)iv.x * 256);
        const bf8v c1 = *(const bf8v*)(base + (size_t)iv.y * 256);
        const bf8v c2 = *(const bf8v*)(base + (size_t)iv.z * 256);
        const bf8v c3 = *(const bf8v*)(base + (size_t)iv.w * 256);
        bf8v ob;
        #pragma unroll
        for (int j = 0; j < 8; ++j) {
          const float s = gv.x * b2f((ushort)c0[j]) + gv.y * b2f((ushort)c1[j])
                        + gv.z * b2f((ushort)c2[j]) + gv.w * b2f((ushort)c3[j]);
          ob[j] = (short)f2b(s);
        }
        *(bf8v*)&samp[u * 8] = ob;
      }
    }
    // stage B(cb, tap=0)
    const ushort* dsrc = dwpk + (size_t)cb * (9 * 256 * 32);
    for (int e = wave; e < 16; e += 8)
      gll16(dsrc + e * 512 + l * 8, (ushort*)bw[0] + e * 512);
    __syncthreads();

    #pragma unroll
    for (int tap = 0; tap < 9; ++tap) {
      if (tap < 8) {
        const ushort* ns = dsrc + (size_t)(tap + 1) * 8192;
        for (int e = wave; e < 16; e += 8)
          gll16(ns + e * 512 + l * 8, (ushort*)bw[(tap + 1) & 1] + e * 512);
      }
      bf8v af[4], bf[2];
      #pragma unroll
      for (int fp = 0; fp < 4; ++fp)
        af[fp] = *(const bf8v*)&samp[(tap * 64 + fp * 16 + ln) * 32 + kc8];
      #pragma unroll
      for (int fo = 0; fo < 2; ++fo)
        bf[fo] = *(const bf8v*)&bw[tap & 1][(wave * 32 + fo * 16 + ln) * 32 + kc8];
      #pragma unroll
      for (int fp = 0; fp < 4; ++fp)
        #pragma unroll
        for (int fo = 0; fo < 2; ++fo)
          acc[fp][fo] = __builtin_amdgcn_mfma_f32_16x16x32_bf16(af[fp], bf[fo], acc[fp][fo], 0, 0, 0);
      __syncthreads();
    }
  }

  // epilogue: D row = px(j) = (l>>4)*4+r, col = o = l&15
  #pragma unroll
  for (int fp = 0; fp < 4; ++fp) {
    #pragma unroll
    for (int fo = 0; fo < 2; ++fo) {
      const f32x4 a = acc[fp][fo];
      const int o = wave * 32 + fo * 16 + ln;
      const int j0 = fp * 16 + (l >> 4) * 4;
      const size_t base = (((size_t)b * CH + o) * HW + i) * HW + j0;
      const float4 xv = *(const float4*)&x[base];
      float4 r; r.x = a[0] + xv.x; r.y = a[1] + xv.y; r.z = a[2] + xv.z; r.w = a[3] + xv.w;
      *(float4*)&out[base] = r;
    }
  }
}

// ---------------------------------------------------------------------------
extern "C" void kernel_launch(void* const* d_in, const int* in_sizes, int n_in,
                              void* d_out, int out_size, void* d_ws, size_t ws_size,
                              hipStream_t stream) {
  (void)in_sizes; (void)n_in; (void)out_size; (void)ws_size;
  const float* x  = (const float*)d_in[0];
  const float* w1 = (const float*)d_in[1];
  const float* b1 = (const float*)d_in[2];
  const float* w2 = (const float*)d_in[3];
  const float* b2 = (const float*)d_in[4];
  const float* pw = (const float*)d_in[5];
  const float* pb = (const float*)d_in[6];
  const float* dw = (const float*)d_in[7];
  float* out = (float*)d_out;

  char* w = (char*)d_ws;
  size_t off = 0;
  auto carve = [&](size_t bytes) { char* p = w + off; off += (bytes + 255) & ~(size_t)255; return p; };
  ushort* xpad  = (ushort*)carve(8929280);   // 4*4356*256*2 + 8KB slack
  ushort* res1  = (ushort*)carve(8929280);
  ushort* res2  = (ushort*)carve(8929280);
  float*  xt    = (float*) carve(16777216);
  ushort* wpk1  = (ushort*)carve(1179648);
  ushort* wpk2  = (ushort*)carve(1179648);
  ushort* wpkO  = (ushort*)carve(147456);
  ushort* dwpk  = (ushort*)carve(1179648);
  float*  pbias = (float*) carve(256);
  float*  offs  = (float*) carve(2097152);
  float*  table = (float*) carve(4718592);

  hipMemsetAsync(xpad, 0, 8929280, stream);
  hipMemsetAsync(res1, 0, 8929280, stream);
  hipMemsetAsync(res2, 0, 8929280, stream);

  pack_w_k<<<900, 256, 0, stream>>>(w1, w2, dw, pw, pb, wpk1, wpk2, dwpk, wpkO, pbias);
  pack_x_k<<<256, 256, 0, stream>>>(x, xpad, xt);
  conv_mfma<128, 0><<<256, 256, 0, stream>>>(xpad, wpk1, b1, xt, res1);
  conv_mfma<128, 1><<<256, 256, 0, stream>>>(res1, wpk2, b2, nullptr, res2);
  conv_mfma<32, 2><<<128, 256, 0, stream>>>(res2, wpkO, pbias, nullptr, offs);
  build_table_k<<<576, 256, 0, stream>>>(offs, table);
  deform_mfma<<<NB * HW, 512, 0, stream>>>(res2, table, dwpk, x, out);
}